// Round 6
// baseline (524.461 us; speedup 1.0000x reference)
//
#include <hip/hip_runtime.h>

#define NPTS 120000
#define NROW 120064   // padded row count (multiple of 256)
#define NB   60000
#define TAPS 27
#define NBLK (NROW / 128)   // 938 conv blocks

typedef short  short8 __attribute__((ext_vector_type(8)));
typedef float  f32x4  __attribute__((ext_vector_type(4)));

__device__ __forceinline__ float bf2f(unsigned short u) {
  unsigned v = ((unsigned)u) << 16;
  float f; __builtin_memcpy(&f, &v, 4); return f;
}
__device__ __forceinline__ unsigned short f2bf(float f) {
  unsigned v; __builtin_memcpy(&v, &f, 4);
  v = v + 0x7FFFu + ((v >> 16) & 1u);   // RNE (finite values only)
  return (unsigned short)(v >> 16);
}

// ---- invert kernel map: nbr[k*NROW + out_row] = in_row (else -1 from memset) ----
__global__ __launch_bounds__(256) void k_build_nbr(const int* __restrict__ oi,
                                                   const int* __restrict__ ii,
                                                   int* __restrict__ nbr) {
  int g = blockIdx.x * 256 + threadIdx.x;
  if (g >= TAPS * NPTS) return;
  int o = oi[g];
  if (o < NPTS) nbr[(g / NPTS) * NROW + o] = ii[g];
}

// ---- repack w_blocks (f32, 4 layers x 27 x 64 x 64) into bf16 MFMA B-fragment order ----
__global__ __launch_bounds__(256) void k_repack(const float* __restrict__ w,
                                                unsigned short* __restrict__ wp) {
  int g = blockIdx.x * 256 + threadIdx.x;          // 108*4096 total
  int e = g & 7, l = (g >> 3) & 63, f = (g >> 9) & 7, rest = g >> 12; // rest = L*27+k
  int t = f >> 1, h = f & 1;
  int kk = h * 32 + (l >> 4) * 8 + e;
  int cc = t * 16 + (l & 15);
  wp[g] = f2bf(w[(rest * 64 + kk) * 64 + cc]);
}

// ---- stats pass 1 (f32 input, first IN only) ----
__global__ __launch_bounds__(256) void k_stats1_f32(const float* __restrict__ F,
                                                    float* __restrict__ P) {
  int lane = threadIdx.x & 63, wave = threadIdx.x >> 6;
  int batch = blockIdx.x >> 7, bb = blockIdx.x & 127;
  const float* Fb = F + (size_t)batch * NB * 64;
  float s = 0.f, ss = 0.f;
  for (int r = bb * 4 + wave; r < NB; r += 512) {
    float v = Fb[(size_t)r * 64 + lane];
    s += v; ss += v * v;
  }
  __shared__ float ls[4][64], lss[4][64];
  ls[wave][lane] = s; lss[wave][lane] = ss;
  __syncthreads();
  if (threadIdx.x < 64) {
    float S  = ls[0][lane] + ls[1][lane] + ls[2][lane] + ls[3][lane];
    float SS = lss[0][lane] + lss[1][lane] + lss[2][lane] + lss[3][lane];
    P[blockIdx.x * 128 + lane]      = S;
    P[blockIdx.x * 128 + 64 + lane] = SS;
  }
}

// ---- stats pass 2 (for the f32 first IN: 256 partial blocks of 128) ----
__global__ void k_stats2(const float* __restrict__ P, float* __restrict__ MRS) {
  int t = threadIdx.x;
  if (t >= 128) return;
  int b = t >> 6, c = t & 63;
  float S = 0.f, SS = 0.f;
  for (int blk = 0; blk < 128; ++blk) {
    S  += P[(b * 128 + blk) * 128 + c];
    SS += P[(b * 128 + blk) * 128 + 64 + c];
  }
  float mean = S * (1.f / NB);
  float var  = SS * (1.f / NB) - mean * mean;
  MRS[b * 128 + c]      = mean;
  MRS[b * 128 + 64 + c] = rsqrtf(var + 1e-5f);
}

// ---- stats pass 2 for conv-fused partials: P2[blk][bs*64+col], bs=batch*2+stat ----
__global__ void k_stats2f(const float* __restrict__ P, float* __restrict__ MRS) {
  int t = threadIdx.x;   // 256
  float S = 0.f;
  for (int blk = 0; blk < NBLK; ++blk) S += P[(size_t)blk * 256 + t];
  __shared__ float sm[256];
  sm[t] = S;
  __syncthreads();
  if (t < 128) {
    int b = t >> 6, c = t & 63;
    float mean = sm[(b * 2 + 0) * 64 + c] * (1.f / NB);
    float var  = sm[(b * 2 + 1) * 64 + c] * (1.f / NB) - mean * mean;
    MRS[b * 128 + c]      = mean;
    MRS[b * 128 + 64 + c] = rsqrtf(var + 1e-5f);
  }
}

// ---- first apply: f32 feats -> bf16 X, relu(norm) ----
__global__ __launch_bounds__(256) void k_apply_f2b(const float* __restrict__ F,
                                                   const float* __restrict__ MRS,
                                                   unsigned short* __restrict__ O) {
  int i = blockIdx.x * 256 + threadIdx.x;          // 960000 groups of 8
  int r = i >> 3, cb = (i & 7) * 8;
  int b = (r >= NB) ? 1 : 0;
  f32x4 v0 = *((const f32x4*)F + i * 2);
  f32x4 v1 = *((const f32x4*)F + i * 2 + 1);
  short8 o;
#pragma unroll
  for (int e = 0; e < 4; ++e) {
    float f = (v0[e] - MRS[b * 128 + cb + e]) * MRS[b * 128 + 64 + cb + e];
    o[e] = (short)f2bf(fmaxf(f, 0.f));
    float g = (v1[e] - MRS[b * 128 + cb + 4 + e]) * MRS[b * 128 + 64 + cb + 4 + e];
    o[e + 4] = (short)f2bf(fmaxf(g, 0.f));
  }
  *((short8*)O + i) = o;
}

// ---- O = relu(norm(F)), bf16 -> bf16 (in-place safe) ----
__global__ __launch_bounds__(256) void k_apply_bf(const unsigned short* __restrict__ F,
                                                  const float* __restrict__ MRS,
                                                  unsigned short* __restrict__ O) {
  int i = blockIdx.x * 256 + threadIdx.x;
  int r = i >> 3, cb = (i & 7) * 8;
  int b = (r >= NB) ? 1 : 0;
  short8 v = *((const short8*)F + i);
  short8 o;
#pragma unroll
  for (int e = 0; e < 8; ++e) {
    float f = bf2f((unsigned short)v[e]);
    f = (f - MRS[b * 128 + cb + e]) * MRS[b * 128 + 64 + cb + e];
    o[e] = (short)f2bf(fmaxf(f, 0.f));
  }
  *((short8*)O + i) = o;
}

// ---- X = relu(norm(H2) + X), bf16 ----
__global__ __launch_bounds__(256) void k_apply_res_bf(const unsigned short* __restrict__ H2,
                                                      const float* __restrict__ MRS,
                                                      unsigned short* __restrict__ X) {
  int i = blockIdx.x * 256 + threadIdx.x;
  int r = i >> 3, cb = (i & 7) * 8;
  int b = (r >= NB) ? 1 : 0;
  short8 v = *((const short8*)H2 + i);
  short8 xv = *((const short8*)X + i);
  short8 o;
#pragma unroll
  for (int e = 0; e < 8; ++e) {
    float f = bf2f((unsigned short)v[e]);
    f = (f - MRS[b * 128 + cb + e]) * MRS[b * 128 + 64 + cb + e];
    f += bf2f((unsigned short)xv[e]);
    o[e] = (short)f2bf(fmaxf(f, 0.f));
  }
  *((short8*)X + i) = o;
}

// ---- gather-MFMA sparse conv 64->64 (32 rows/wave, 128/block) + fused IN stats ----
__global__ __launch_bounds__(256) void k_conv64s(const unsigned short* __restrict__ X,
                                                 const unsigned short* __restrict__ WP,
                                                 const int* __restrict__ nbr,
                                                 unsigned short* __restrict__ Y,
                                                 float* __restrict__ P) {
  const int lane = threadIdx.x & 63, wave = threadIdx.x >> 6;
  const int j0w = blockIdx.x * 128 + wave * 32;
  const int lrow = lane & 15, lk = lane >> 4;
  f32x4 acc[2][4];   // [rowgroup][coltile]
#pragma unroll
  for (int g = 0; g < 2; ++g)
#pragma unroll
    for (int c = 0; c < 4; ++c) acc[g][c] = (f32x4){0.f, 0.f, 0.f, 0.f};

  for (int k = 0; k < TAPS; ++k) {
    const int* np = nbr + (size_t)k * NROW + j0w + lrow;
    int i0 = np[0], i1 = np[16];
    if (__ballot(i0 >= 0 || i1 >= 0) == 0ull) continue;
    short8 a00 = {0,0,0,0,0,0,0,0}, a01 = {0,0,0,0,0,0,0,0};
    short8 a10 = {0,0,0,0,0,0,0,0}, a11 = {0,0,0,0,0,0,0,0};
    if (i0 >= 0) {
      const unsigned short* rp = X + (size_t)i0 * 64 + lk * 8;
      a00 = *(const short8*)rp; a01 = *(const short8*)(rp + 32);
    }
    if (i1 >= 0) {
      const unsigned short* rp = X + (size_t)i1 * 64 + lk * 8;
      a10 = *(const short8*)rp; a11 = *(const short8*)(rp + 32);
    }
    const unsigned short* wpk = WP + k * 4096 + lane * 8;
#pragma unroll
    for (int ct = 0; ct < 4; ++ct) {
      short8 b0 = *(const short8*)(wpk + ct * 1024);
      short8 b1 = *(const short8*)(wpk + ct * 1024 + 512);
      acc[0][ct] = __builtin_amdgcn_mfma_f32_16x16x32_bf16(a00, b0, acc[0][ct], 0, 0, 0);
      acc[0][ct] = __builtin_amdgcn_mfma_f32_16x16x32_bf16(a01, b1, acc[0][ct], 0, 0, 0);
      acc[1][ct] = __builtin_amdgcn_mfma_f32_16x16x32_bf16(a10, b0, acc[1][ct], 0, 0, 0);
      acc[1][ct] = __builtin_amdgcn_mfma_f32_16x16x32_bf16(a11, b1, acc[1][ct], 0, 0, 0);
    }
  }
  // C/D: col = lane&15 (+ct*16), row = (lane>>4)*4 + reg (+g*16)
#pragma unroll
  for (int g = 0; g < 2; ++g) {
    unsigned short* yp = Y + (size_t)(j0w + g * 16 + lk * 4) * 64 + lrow;
#pragma unroll
    for (int r = 0; r < 4; ++r) {
      yp[r * 64 +  0] = f2bf(acc[g][0][r]);
      yp[r * 64 + 16] = f2bf(acc[g][1][r]);
      yp[r * 64 + 32] = f2bf(acc[g][2][r]);
      yp[r * 64 + 48] = f2bf(acc[g][3][r]);
    }
  }
  // fused IN stats: per-lane sum/sumsq over its 8 rows, batch-split
  float s[4][2], q[4][2];
#pragma unroll
  for (int ct = 0; ct < 4; ++ct) { s[ct][0] = s[ct][1] = q[ct][0] = q[ct][1] = 0.f; }
#pragma unroll
  for (int g = 0; g < 2; ++g) {
    int rowbase = j0w + g * 16 + lk * 4;
#pragma unroll
    for (int r = 0; r < 4; ++r) {
      int bt = (rowbase + r) >= NB;
#pragma unroll
      for (int ct = 0; ct < 4; ++ct) {
        float v = acc[g][ct][r];
        s[ct][bt] += v; q[ct][bt] += v * v;
      }
    }
  }
  __shared__ float sred[4][4][4][64];   // [wave][lk][batch*2+stat][col]
#pragma unroll
  for (int ct = 0; ct < 4; ++ct)
#pragma unroll
    for (int b = 0; b < 2; ++b) {
      sred[wave][lk][b * 2 + 0][ct * 16 + lrow] = s[ct][b];
      sred[wave][lk][b * 2 + 1][ct * 16 + lrow] = q[ct][b];
    }
  __syncthreads();
  int t = threadIdx.x;
  float S = 0.f;
#pragma unroll
  for (int w = 0; w < 4; ++w)
#pragma unroll
    for (int l2 = 0; l2 < 4; ++l2)
      S += sred[w][l2][t >> 6][t & 63];
  P[(size_t)blockIdx.x * 256 + t] = S;
}

// ---- final stage 1: D[k][i] = X[i] . WF[k]  (MFMA GEMM 120064x64 @ 64x27) ----
__global__ __launch_bounds__(256) void k_dfin(const unsigned short* __restrict__ X,
                                              const float* __restrict__ WF,
                                              float* __restrict__ D) {
  const int lane = threadIdx.x & 63, wave = threadIdx.x >> 6;
  const int j0 = blockIdx.x * 64 + wave * 16;
  const int lrow = lane & 15, lk = lane >> 4;
  const unsigned short* rp = X + (size_t)(j0 + lrow) * 64 + lk * 8;
  short8 a0 = *(const short8*)rp;
  short8 a1 = *(const short8*)(rp + 32);
  short8 b[2][2];
#pragma unroll
  for (int ct = 0; ct < 2; ++ct) {
    int col = ct * 16 + lrow;
#pragma unroll
    for (int h = 0; h < 2; ++h) {
#pragma unroll
      for (int e = 0; e < 8; ++e)
        b[ct][h][e] = (col < TAPS) ? (short)f2bf(WF[col * 64 + h * 32 + lk * 8 + e]) : (short)0;
    }
  }
  f32x4 acc0 = {0,0,0,0}, acc1 = {0,0,0,0};
  acc0 = __builtin_amdgcn_mfma_f32_16x16x32_bf16(a0, b[0][0], acc0, 0, 0, 0);
  acc0 = __builtin_amdgcn_mfma_f32_16x16x32_bf16(a1, b[0][1], acc0, 0, 0, 0);
  acc1 = __builtin_amdgcn_mfma_f32_16x16x32_bf16(a0, b[1][0], acc1, 0, 0, 0);
  acc1 = __builtin_amdgcn_mfma_f32_16x16x32_bf16(a1, b[1][1], acc1, 0, 0, 0);
  float* dp0 = D + (size_t)lrow * NROW + j0 + lk * 4;
  float* dp1 = D + (size_t)(16 + lrow) * NROW + j0 + lk * 4;
#pragma unroll
  for (int r = 0; r < 4; ++r) { dp0[r] = acc0[r]; dp1[r] = acc1[r]; }
}

// ---- final stage 2: out[j] = bias + sum_k D[k][nbr[k][j]] ----
__global__ __launch_bounds__(256) void k_gfin(const float* __restrict__ D,
                                              const int* __restrict__ nbr,
                                              const float* __restrict__ BF,
                                              float* __restrict__ out) {
  int j = blockIdx.x * 256 + threadIdx.x;
  if (j >= NPTS) return;
  float acc = BF[0];
#pragma unroll
  for (int k = 0; k < TAPS; ++k) {
    int idx = nbr[(size_t)k * NROW + j];
    if (idx >= 0) acc += D[(size_t)k * NROW + idx];
  }
  out[j] = acc;
}

extern "C" void kernel_launch(void* const* d_in, const int* in_sizes, int n_in,
                              void* d_out, int out_size, void* d_ws, size_t ws_size,
                              hipStream_t stream) {
  (void)in_sizes; (void)n_in; (void)out_size; (void)ws_size;
  const float* feats = (const float*)d_in[0];
  const float* wblk  = (const float*)d_in[1];
  const float* wfin  = (const float*)d_in[2];
  const float* bfin  = (const float*)d_in[3];
  const int* in_idx  = (const int*)d_in[4];
  const int* out_idx = (const int*)d_in[5];

  char* p = (char*)d_ws;
  size_t off = 0;
  auto carve = [&](size_t bytes) {
    void* r = p + off; off += (bytes + 255) & ~(size_t)255; return r;
  };
  int*            nbr = (int*)carve((size_t)TAPS * NROW * 4);             // 12.97 MB
  unsigned short* Xb  = (unsigned short*)carve((size_t)NROW * 64 * 2);    // 15.37 MB
  unsigned short* Hb  = (unsigned short*)carve((size_t)NROW * 64 * 2);
  unsigned short* H2b = (unsigned short*)carve((size_t)NROW * 64 * 2);
  unsigned short* WP  = (unsigned short*)carve(108u * 4096u * 2);         // 0.88 MB
  float*          D   = (float*)carve((size_t)32 * NROW * 4);             // 15.4 MB (32 rows: dfin writes cols 0..31)
  float*          P   = (float*)carve(256 * 128 * 4);                     // first-IN partials
  float*          P2  = (float*)carve((size_t)NBLK * 256 * 4);            // conv-fused partials
  float*          MRS = (float*)carve(256 * 4);

  hipMemsetAsync(nbr, 0xFF, (size_t)TAPS * NROW * 4, stream);
  k_build_nbr<<<(TAPS * NPTS + 255) / 256, 256, 0, stream>>>(out_idx, in_idx, nbr);
  k_repack<<<1728, 256, 0, stream>>>(wblk, WP);

  // x = relu(IN(feats))
  k_stats1_f32<<<256, 256, 0, stream>>>(feats, P);
  k_stats2<<<1, 128, 0, stream>>>(P, MRS);
  k_apply_f2b<<<3750, 256, 0, stream>>>(feats, MRS, Xb);

  // block 0
  k_conv64s<<<NBLK, 256, 0, stream>>>(Xb, WP + 0 * 110592, nbr, Hb, P2);
  k_stats2f<<<1, 256, 0, stream>>>(P2, MRS);
  k_apply_bf<<<3750, 256, 0, stream>>>(Hb, MRS, Hb);
  k_conv64s<<<NBLK, 256, 0, stream>>>(Hb, WP + 1 * 110592, nbr, H2b, P2);
  k_stats2f<<<1, 256, 0, stream>>>(P2, MRS);
  k_apply_res_bf<<<3750, 256, 0, stream>>>(H2b, MRS, Xb);

  // block 1
  k_conv64s<<<NBLK, 256, 0, stream>>>(Xb, WP + 2 * 110592, nbr, Hb, P2);
  k_stats2f<<<1, 256, 0, stream>>>(P2, MRS);
  k_apply_bf<<<3750, 256, 0, stream>>>(Hb, MRS, Hb);
  k_conv64s<<<NBLK, 256, 0, stream>>>(Hb, WP + 3 * 110592, nbr, H2b, P2);
  k_stats2f<<<1, 256, 0, stream>>>(P2, MRS);
  k_apply_res_bf<<<3750, 256, 0, stream>>>(H2b, MRS, Xb);

  // final 64->1 conv + bias: D = X.WF^T then gather-sum
  k_dfin<<<NROW / 64, 256, 0, stream>>>(Xb, wfin, D);
  k_gfin<<<NROW / 256, 256, 0, stream>>>(D, nbr, bfin, (float*)d_out);
}

// Round 7
// 451.445 us; speedup vs baseline: 1.1617x; 1.1617x over previous
//
#include <hip/hip_runtime.h>

#define NPTS 120000
#define NROW 120064   // padded row count (multiple of 256); row NROW itself = zero row
#define NB   60000
#define TAPS 27
#define NBLK (NROW / 128)   // 938 conv blocks

typedef short  short8 __attribute__((ext_vector_type(8)));
typedef float  f32x4  __attribute__((ext_vector_type(4)));

__device__ __forceinline__ float bf2f(unsigned short u) {
  unsigned v = ((unsigned)u) << 16;
  float f; __builtin_memcpy(&f, &v, 4); return f;
}
__device__ __forceinline__ unsigned short f2bf(float f) {
  unsigned v; __builtin_memcpy(&v, &f, 4);
  v = v + 0x7FFFu + ((v >> 16) & 1u);   // RNE (finite values only)
  return (unsigned short)(v >> 16);
}

// ---- invert kernel map: nbr[k*NROW + out_row] = in_row (else -1 from memset) ----
__global__ __launch_bounds__(256) void k_build_nbr(const int* __restrict__ oi,
                                                   const int* __restrict__ ii,
                                                   int* __restrict__ nbr) {
  int g = blockIdx.x * 256 + threadIdx.x;
  if (g >= TAPS * NPTS) return;
  int o = oi[g];
  if (o < NPTS) nbr[(g / NPTS) * NROW + o] = ii[g];
}

// ---- repack w_blocks (f32, 4 layers x 27 x 64 x 64) into bf16 MFMA B-fragment order ----
__global__ __launch_bounds__(256) void k_repack(const float* __restrict__ w,
                                                unsigned short* __restrict__ wp) {
  int g = blockIdx.x * 256 + threadIdx.x;          // 108*4096 total
  int e = g & 7, l = (g >> 3) & 63, f = (g >> 9) & 7, rest = g >> 12; // rest = L*27+k
  int t = f >> 1, h = f & 1;
  int kk = h * 32 + (l >> 4) * 8 + e;
  int cc = t * 16 + (l & 15);
  wp[g] = f2bf(w[(rest * 64 + kk) * 64 + cc]);
}

// ---- stats pass 1 (f32 input, first IN): atomic partials into SM[bs*64+c] ----
__global__ __launch_bounds__(256) void k_stats1_f32(const float* __restrict__ F,
                                                    float* __restrict__ SM) {
  int lane = threadIdx.x & 63, wave = threadIdx.x >> 6;
  int batch = blockIdx.x >> 7, bb = blockIdx.x & 127;
  const float* Fb = F + (size_t)batch * NB * 64;
  float s = 0.f, ss = 0.f;
  for (int r = bb * 4 + wave; r < NB; r += 512) {
    float v = Fb[(size_t)r * 64 + lane];
    s += v; ss += v * v;
  }
  __shared__ float ls[4][64], lss[4][64];
  ls[wave][lane] = s; lss[wave][lane] = ss;
  __syncthreads();
  if (threadIdx.x < 64) {
    float S  = ls[0][lane] + ls[1][lane] + ls[2][lane] + ls[3][lane];
    float SS = lss[0][lane] + lss[1][lane] + lss[2][lane] + lss[3][lane];
    atomicAdd(&SM[(batch * 2 + 0) * 64 + lane], S);
    atomicAdd(&SM[(batch * 2 + 1) * 64 + lane], SS);
  }
}

// ---- first apply: f32 feats -> bf16 X, relu(norm), MRS computed inline from SM ----
__global__ __launch_bounds__(256) void k_apply_f2b(const float* __restrict__ F,
                                                   const float* __restrict__ SM,
                                                   unsigned short* __restrict__ O) {
  int i = blockIdx.x * 256 + threadIdx.x;          // 960000 groups of 8
  int r = i >> 3, cb = (i & 7) * 8;
  int b = (r >= NB) ? 1 : 0;
  f32x4 v0 = *((const f32x4*)F + i * 2);
  f32x4 v1 = *((const f32x4*)F + i * 2 + 1);
  short8 o;
#pragma unroll
  for (int e = 0; e < 8; ++e) {
    float mean = SM[(b * 2 + 0) * 64 + cb + e] * (1.f / NB);
    float var  = SM[(b * 2 + 1) * 64 + cb + e] * (1.f / NB) - mean * mean;
    float rstd = rsqrtf(var + 1e-5f);
    float x = (e < 4) ? v0[e & 3] : v1[e & 3];
    o[e] = (short)f2bf(fmaxf((x - mean) * rstd, 0.f));
  }
  *((short8*)O + i) = o;
}

// ---- O = relu(norm(F)), bf16 -> bf16, MRS inline ----
__global__ __launch_bounds__(256) void k_apply_bf(const unsigned short* __restrict__ F,
                                                  const float* __restrict__ SM,
                                                  unsigned short* __restrict__ O) {
  int i = blockIdx.x * 256 + threadIdx.x;
  int r = i >> 3, cb = (i & 7) * 8;
  int b = (r >= NB) ? 1 : 0;
  short8 v = *((const short8*)F + i);
  short8 o;
#pragma unroll
  for (int e = 0; e < 8; ++e) {
    float mean = SM[(b * 2 + 0) * 64 + cb + e] * (1.f / NB);
    float var  = SM[(b * 2 + 1) * 64 + cb + e] * (1.f / NB) - mean * mean;
    float rstd = rsqrtf(var + 1e-5f);
    float f = (bf2f((unsigned short)v[e]) - mean) * rstd;
    o[e] = (short)f2bf(fmaxf(f, 0.f));
  }
  *((short8*)O + i) = o;
}

// ---- X = relu(norm(H2) + X), bf16, MRS inline ----
__global__ __launch_bounds__(256) void k_apply_res_bf(const unsigned short* __restrict__ H2,
                                                      const float* __restrict__ SM,
                                                      unsigned short* __restrict__ X) {
  int i = blockIdx.x * 256 + threadIdx.x;
  int r = i >> 3, cb = (i & 7) * 8;
  int b = (r >= NB) ? 1 : 0;
  short8 v = *((const short8*)H2 + i);
  short8 xv = *((const short8*)X + i);
  short8 o;
#pragma unroll
  for (int e = 0; e < 8; ++e) {
    float mean = SM[(b * 2 + 0) * 64 + cb + e] * (1.f / NB);
    float var  = SM[(b * 2 + 1) * 64 + cb + e] * (1.f / NB) - mean * mean;
    float rstd = rsqrtf(var + 1e-5f);
    float f = (bf2f((unsigned short)v[e]) - mean) * rstd + bf2f((unsigned short)xv[e]);
    o[e] = (short)f2bf(fmaxf(f, 0.f));
  }
  *((short8*)X + i) = o;
}

// ---- gather-MFMA sparse conv 64->64, 32 rows/wave, 2-deep tap pipeline, fused stats ----
__global__ __launch_bounds__(256) void k_conv64s(const unsigned short* __restrict__ X,
                                                 const unsigned short* __restrict__ WP,
                                                 const int* __restrict__ nbr,
                                                 unsigned short* __restrict__ Y,
                                                 float* __restrict__ SM) {
  const int lane = threadIdx.x & 63, wave = threadIdx.x >> 6;
  const int j0w = blockIdx.x * 128 + wave * 32;
  const int lrow = lane & 15, lk = lane >> 4;
  const int nb0 = j0w + lrow;
  f32x4 acc[2][4];
#pragma unroll
  for (int g = 0; g < 2; ++g)
#pragma unroll
    for (int c = 0; c < 4; ++c) acc[g][c] = (f32x4){0.f, 0.f, 0.f, 0.f};

  short8 aA[2][2], aB[2][2];

  auto GATHER = [&](int k, short8 (&a)[2][2]) {
    const int* np = nbr + (size_t)k * NROW + nb0;
    int i0 = np[0], i1 = np[16];
    const unsigned short* r0 = X + (size_t)(i0 >= 0 ? i0 : NROW) * 64 + lk * 8;
    const unsigned short* r1 = X + (size_t)(i1 >= 0 ? i1 : NROW) * 64 + lk * 8;
    a[0][0] = *(const short8*)r0; a[0][1] = *(const short8*)(r0 + 32);
    a[1][0] = *(const short8*)r1; a[1][1] = *(const short8*)(r1 + 32);
  };
  auto TAP = [&](int k, short8 (&a)[2][2]) {
    const unsigned short* wpk = WP + k * 4096 + lane * 8;
#pragma unroll
    for (int ct = 0; ct < 4; ++ct) {
      short8 b0 = *(const short8*)(wpk + ct * 1024);
      short8 b1 = *(const short8*)(wpk + ct * 1024 + 512);
      acc[0][ct] = __builtin_amdgcn_mfma_f32_16x16x32_bf16(a[0][0], b0, acc[0][ct], 0, 0, 0);
      acc[0][ct] = __builtin_amdgcn_mfma_f32_16x16x32_bf16(a[0][1], b1, acc[0][ct], 0, 0, 0);
      acc[1][ct] = __builtin_amdgcn_mfma_f32_16x16x32_bf16(a[1][0], b0, acc[1][ct], 0, 0, 0);
      acc[1][ct] = __builtin_amdgcn_mfma_f32_16x16x32_bf16(a[1][1], b1, acc[1][ct], 0, 0, 0);
    }
  };

  GATHER(0, aA);
#pragma unroll
  for (int kk = 0; kk < TAPS; kk += 2) {
    if (kk + 1 < TAPS) GATHER(kk + 1, aB);
    TAP(kk, aA);
    if (kk + 1 < TAPS) {
      if (kk + 2 < TAPS) GATHER(kk + 2, aA);
      TAP(kk + 1, aB);
    }
  }

  // C/D: col = lane&15 (+ct*16), row = (lane>>4)*4 + reg (+g*16)
#pragma unroll
  for (int g = 0; g < 2; ++g) {
    unsigned short* yp = Y + (size_t)(j0w + g * 16 + lk * 4) * 64 + lrow;
#pragma unroll
    for (int r = 0; r < 4; ++r) {
      yp[r * 64 +  0] = f2bf(acc[g][0][r]);
      yp[r * 64 + 16] = f2bf(acc[g][1][r]);
      yp[r * 64 + 32] = f2bf(acc[g][2][r]);
      yp[r * 64 + 48] = f2bf(acc[g][3][r]);
    }
  }

  // fused IN stats: per-lane sum/sumsq over its 8 rows, batch-split
  float s[4][2], q[4][2];
#pragma unroll
  for (int ct = 0; ct < 4; ++ct) { s[ct][0] = s[ct][1] = q[ct][0] = q[ct][1] = 0.f; }
#pragma unroll
  for (int g = 0; g < 2; ++g) {
    int rowbase = j0w + g * 16 + lk * 4;
#pragma unroll
    for (int r = 0; r < 4; ++r) {
      int bt = (rowbase + r) >= NB;
#pragma unroll
      for (int ct = 0; ct < 4; ++ct) {
        float v = acc[g][ct][r];
        s[ct][bt] += v; q[ct][bt] += v * v;
      }
    }
  }
  __shared__ float sred[4][4][4][64];   // [wave][lk][batch*2+stat][col]
#pragma unroll
  for (int ct = 0; ct < 4; ++ct)
#pragma unroll
    for (int b = 0; b < 2; ++b) {
      sred[wave][lk][b * 2 + 0][ct * 16 + lrow] = s[ct][b];
      sred[wave][lk][b * 2 + 1][ct * 16 + lrow] = q[ct][b];
    }
  __syncthreads();
  int t = threadIdx.x;
  float S = 0.f;
#pragma unroll
  for (int w = 0; w < 4; ++w)
#pragma unroll
    for (int l2 = 0; l2 < 4; ++l2)
      S += sred[w][l2][t >> 6][t & 63];
  atomicAdd(&SM[t], S);
}

// ---- final stage 1: D[k][i] = X[i] . WF[k]  (MFMA GEMM 120064x64 @ 64x27) ----
__global__ __launch_bounds__(256) void k_dfin(const unsigned short* __restrict__ X,
                                              const float* __restrict__ WF,
                                              float* __restrict__ D) {
  const int lane = threadIdx.x & 63, wave = threadIdx.x >> 6;
  const int j0 = blockIdx.x * 64 + wave * 16;
  const int lrow = lane & 15, lk = lane >> 4;
  const unsigned short* rp = X + (size_t)(j0 + lrow) * 64 + lk * 8;
  short8 a0 = *(const short8*)rp;
  short8 a1 = *(const short8*)(rp + 32);
  short8 b[2][2];
#pragma unroll
  for (int ct = 0; ct < 2; ++ct) {
    int col = ct * 16 + lrow;
#pragma unroll
    for (int h = 0; h < 2; ++h) {
#pragma unroll
      for (int e = 0; e < 8; ++e)
        b[ct][h][e] = (col < TAPS) ? (short)f2bf(WF[col * 64 + h * 32 + lk * 8 + e]) : (short)0;
    }
  }
  f32x4 acc0 = {0,0,0,0}, acc1 = {0,0,0,0};
  acc0 = __builtin_amdgcn_mfma_f32_16x16x32_bf16(a0, b[0][0], acc0, 0, 0, 0);
  acc0 = __builtin_amdgcn_mfma_f32_16x16x32_bf16(a1, b[0][1], acc0, 0, 0, 0);
  acc1 = __builtin_amdgcn_mfma_f32_16x16x32_bf16(a0, b[1][0], acc1, 0, 0, 0);
  acc1 = __builtin_amdgcn_mfma_f32_16x16x32_bf16(a1, b[1][1], acc1, 0, 0, 0);
  float* dp0 = D + (size_t)lrow * NROW + j0 + lk * 4;
  float* dp1 = D + (size_t)(16 + lrow) * NROW + j0 + lk * 4;
#pragma unroll
  for (int r = 0; r < 4; ++r) { dp0[r] = acc0[r]; dp1[r] = acc1[r]; }
}

// ---- final stage 2: out[j] = bias + sum_k D[k][nbr[k][j]] ----
__global__ __launch_bounds__(256) void k_gfin(const float* __restrict__ D,
                                              const int* __restrict__ nbr,
                                              const float* __restrict__ BF,
                                              float* __restrict__ out) {
  int j = blockIdx.x * 256 + threadIdx.x;
  if (j >= NPTS) return;
  float acc = BF[0];
#pragma unroll
  for (int k = 0; k < TAPS; ++k) {
    int idx = nbr[(size_t)k * NROW + j];
    if (idx >= 0) acc += D[(size_t)k * NROW + idx];
  }
  out[j] = acc;
}

extern "C" void kernel_launch(void* const* d_in, const int* in_sizes, int n_in,
                              void* d_out, int out_size, void* d_ws, size_t ws_size,
                              hipStream_t stream) {
  (void)in_sizes; (void)n_in; (void)out_size; (void)ws_size;
  const float* feats = (const float*)d_in[0];
  const float* wblk  = (const float*)d_in[1];
  const float* wfin  = (const float*)d_in[2];
  const float* bfin  = (const float*)d_in[3];
  const int* in_idx  = (const int*)d_in[4];
  const int* out_idx = (const int*)d_in[5];

  char* p = (char*)d_ws;
  size_t off = 0;
  auto carve = [&](size_t bytes) {
    void* r = p + off; off += (bytes + 255) & ~(size_t)255; return r;
  };
  int*            nbr = (int*)carve((size_t)TAPS * NROW * 4);                 // 12.97 MB
  unsigned short* Xb  = (unsigned short*)carve((size_t)(NROW + 1) * 64 * 2);  // +1 zero row
  unsigned short* Hb  = (unsigned short*)carve((size_t)(NROW + 1) * 64 * 2);
  unsigned short* H2b = (unsigned short*)carve((size_t)NROW * 64 * 2);
  unsigned short* WP  = (unsigned short*)carve(108u * 4096u * 2);             // 0.88 MB
  float*          D   = (float*)carve((size_t)32 * NROW * 4);                 // 15.4 MB
  float*          SMa = (float*)carve(5 * 256 * 4);                           // SM0..SM4

  float* SM0 = SMa;
  float* SM1 = SMa + 256;
  float* SM2 = SMa + 512;
  float* SM3 = SMa + 768;
  float* SM4 = SMa + 1024;

  hipMemsetAsync(nbr, 0xFF, (size_t)TAPS * NROW * 4, stream);
  hipMemsetAsync(SMa, 0, 5 * 256 * 4, stream);
  hipMemsetAsync(Xb + (size_t)NROW * 64, 0, 128, stream);   // zero row
  hipMemsetAsync(Hb + (size_t)NROW * 64, 0, 128, stream);   // zero row
  k_build_nbr<<<(TAPS * NPTS + 255) / 256, 256, 0, stream>>>(out_idx, in_idx, nbr);
  k_repack<<<1728, 256, 0, stream>>>(wblk, WP);

  // x = relu(IN(feats))
  k_stats1_f32<<<256, 256, 0, stream>>>(feats, SM0);
  k_apply_f2b<<<3750, 256, 0, stream>>>(feats, SM0, Xb);

  // block 0
  k_conv64s<<<NBLK, 256, 0, stream>>>(Xb, WP + 0 * 110592, nbr, Hb, SM1);
  k_apply_bf<<<3750, 256, 0, stream>>>(Hb, SM1, Hb);
  k_conv64s<<<NBLK, 256, 0, stream>>>(Hb, WP + 1 * 110592, nbr, H2b, SM2);
  k_apply_res_bf<<<3750, 256, 0, stream>>>(H2b, SM2, Xb);

  // block 1
  k_conv64s<<<NBLK, 256, 0, stream>>>(Xb, WP + 2 * 110592, nbr, Hb, SM3);
  k_apply_bf<<<3750, 256, 0, stream>>>(Hb, SM3, Hb);
  k_conv64s<<<NBLK, 256, 0, stream>>>(Hb, WP + 3 * 110592, nbr, H2b, SM4);
  k_apply_res_bf<<<3750, 256, 0, stream>>>(H2b, SM4, Xb);

  // final 64->1 conv + bias: D = X.WF^T then gather-sum
  k_dfin<<<NROW / 64, 256, 0, stream>>>(Xb, wfin, D);
  k_gfin<<<NROW / 256, 256, 0, stream>>>(D, nbr, bfin, (float*)d_out);
}

// Round 8
// 451.391 us; speedup vs baseline: 1.1619x; 1.0001x over previous
//
#include <hip/hip_runtime.h>

#define NPTS 120000
#define NROW 120064   // padded row count (multiple of 256); row NROW itself = zero row
#define NB   60000
#define TAPS 27
#define NBLK (NROW / 128)   // 938 conv blocks

typedef short  short8 __attribute__((ext_vector_type(8)));
typedef float  f32x4  __attribute__((ext_vector_type(4)));
typedef unsigned int u32;
#define GLB __attribute__((address_space(1)))
#define LDS __attribute__((address_space(3)))

__device__ __forceinline__ float bf2f(unsigned short u) {
  unsigned v = ((unsigned)u) << 16;
  float f; __builtin_memcpy(&f, &v, 4); return f;
}
__device__ __forceinline__ unsigned short f2bf(float f) {
  unsigned v; __builtin_memcpy(&v, &f, 4);
  v = v + 0x7FFFu + ((v >> 16) & 1u);   // RNE (finite values only)
  return (unsigned short)(v >> 16);
}

// ---- invert kernel map: nbr[k*NROW + out_row] = in_row (else -1 from memset) ----
__global__ __launch_bounds__(256) void k_build_nbr(const int* __restrict__ oi,
                                                   const int* __restrict__ ii,
                                                   int* __restrict__ nbr) {
  int g = blockIdx.x * 256 + threadIdx.x;
  if (g >= TAPS * NPTS) return;
  int o = oi[g];
  if (o < NPTS) nbr[(g / NPTS) * NROW + o] = ii[g];
}

// ---- repack w_blocks (f32, 4 layers x 27 x 64 x 64) into bf16 MFMA B-fragment order ----
__global__ __launch_bounds__(256) void k_repack(const float* __restrict__ w,
                                                unsigned short* __restrict__ wp) {
  int g = blockIdx.x * 256 + threadIdx.x;          // 108*4096 total
  int e = g & 7, l = (g >> 3) & 63, f = (g >> 9) & 7, rest = g >> 12; // rest = L*27+k
  int t = f >> 1, h = f & 1;
  int kk = h * 32 + (l >> 4) * 8 + e;
  int cc = t * 16 + (l & 15);
  wp[g] = f2bf(w[(rest * 64 + kk) * 64 + cc]);
}

// ---- stats pass 1 (f32 input, first IN): atomic partials into SM[bs*64+c] ----
__global__ __launch_bounds__(256) void k_stats1_f32(const float* __restrict__ F,
                                                    float* __restrict__ SM) {
  int lane = threadIdx.x & 63, wave = threadIdx.x >> 6;
  int batch = blockIdx.x >> 7, bb = blockIdx.x & 127;
  const float* Fb = F + (size_t)batch * NB * 64;
  float s = 0.f, ss = 0.f;
  for (int r = bb * 4 + wave; r < NB; r += 512) {
    float v = Fb[(size_t)r * 64 + lane];
    s += v; ss += v * v;
  }
  __shared__ float ls[4][64], lss[4][64];
  ls[wave][lane] = s; lss[wave][lane] = ss;
  __syncthreads();
  if (threadIdx.x < 64) {
    float S  = ls[0][lane] + ls[1][lane] + ls[2][lane] + ls[3][lane];
    float SS = lss[0][lane] + lss[1][lane] + lss[2][lane] + lss[3][lane];
    atomicAdd(&SM[(batch * 2 + 0) * 64 + lane], S);
    atomicAdd(&SM[(batch * 2 + 1) * 64 + lane], SS);
  }
}

// ---- first apply: f32 feats -> bf16 X, relu(norm), MRS computed inline from SM ----
__global__ __launch_bounds__(256) void k_apply_f2b(const float* __restrict__ F,
                                                   const float* __restrict__ SM,
                                                   unsigned short* __restrict__ O) {
  int i = blockIdx.x * 256 + threadIdx.x;          // 960000 groups of 8
  int r = i >> 3, cb = (i & 7) * 8;
  int b = (r >= NB) ? 1 : 0;
  f32x4 v0 = *((const f32x4*)F + i * 2);
  f32x4 v1 = *((const f32x4*)F + i * 2 + 1);
  short8 o;
#pragma unroll
  for (int e = 0; e < 8; ++e) {
    float mean = SM[(b * 2 + 0) * 64 + cb + e] * (1.f / NB);
    float var  = SM[(b * 2 + 1) * 64 + cb + e] * (1.f / NB) - mean * mean;
    float rstd = rsqrtf(var + 1e-5f);
    float x = (e < 4) ? v0[e & 3] : v1[e & 3];
    o[e] = (short)f2bf(fmaxf((x - mean) * rstd, 0.f));
  }
  *((short8*)O + i) = o;
}

// ---- O = relu(norm(F)), bf16 -> bf16, MRS inline ----
__global__ __launch_bounds__(256) void k_apply_bf(const unsigned short* __restrict__ F,
                                                  const float* __restrict__ SM,
                                                  unsigned short* __restrict__ O) {
  int i = blockIdx.x * 256 + threadIdx.x;
  int r = i >> 3, cb = (i & 7) * 8;
  int b = (r >= NB) ? 1 : 0;
  short8 v = *((const short8*)F + i);
  short8 o;
#pragma unroll
  for (int e = 0; e < 8; ++e) {
    float mean = SM[(b * 2 + 0) * 64 + cb + e] * (1.f / NB);
    float var  = SM[(b * 2 + 1) * 64 + cb + e] * (1.f / NB) - mean * mean;
    float rstd = rsqrtf(var + 1e-5f);
    float f = (bf2f((unsigned short)v[e]) - mean) * rstd;
    o[e] = (short)f2bf(fmaxf(f, 0.f));
  }
  *((short8*)O + i) = o;
}

// ---- X = relu(norm(H2) + X), bf16, MRS inline ----
__global__ __launch_bounds__(256) void k_apply_res_bf(const unsigned short* __restrict__ H2,
                                                      const float* __restrict__ SM,
                                                      unsigned short* __restrict__ X) {
  int i = blockIdx.x * 256 + threadIdx.x;
  int r = i >> 3, cb = (i & 7) * 8;
  int b = (r >= NB) ? 1 : 0;
  short8 v = *((const short8*)H2 + i);
  short8 xv = *((const short8*)X + i);
  short8 o;
#pragma unroll
  for (int e = 0; e < 8; ++e) {
    float mean = SM[(b * 2 + 0) * 64 + cb + e] * (1.f / NB);
    float var  = SM[(b * 2 + 1) * 64 + cb + e] * (1.f / NB) - mean * mean;
    float rstd = rsqrtf(var + 1e-5f);
    float f = (bf2f((unsigned short)v[e]) - mean) * rstd + bf2f((unsigned short)xv[e]);
    o[e] = (short)f2bf(fmaxf(f, 0.f));
  }
  *((short8*)X + i) = o;
}

// ---- gather-MFMA sparse conv 64->64, 32 rows/wave, LDS-staged weights, fused stats ----
__global__ __launch_bounds__(256) void k_conv64s(const unsigned short* __restrict__ X,
                                                 const unsigned short* __restrict__ WP,
                                                 const int* __restrict__ nbr,
                                                 unsigned short* __restrict__ Y,
                                                 float* __restrict__ SM) {
  const int lane = threadIdx.x & 63, wave = threadIdx.x >> 6;
  const int t = threadIdx.x;
  const int j0w = blockIdx.x * 128 + wave * 32;
  const int lrow = lane & 15, lk = lane >> 4;
  const int nb0 = j0w + lrow;

  __shared__ unsigned short wbuf[2][4096];   // double-buffered tap weights (8KB each)
  __shared__ float sred[4][4][4][64];        // stats reduction (16KB)

  // stage tap 0 into wbuf[0]: lds[t*16B] = WP[k*8KB + t*16B]  (linear lane order)
  {
    const unsigned short* g = WP;
    __builtin_amdgcn_global_load_lds((GLB const u32*)(g + t * 8),
                                     (LDS u32*)&wbuf[0][t * 8], 16, 0, 0);
    __builtin_amdgcn_global_load_lds((GLB const u32*)(g + (t + 256) * 8),
                                     (LDS u32*)&wbuf[0][(t + 256) * 8], 16, 0, 0);
  }
  __syncthreads();   // drains vmcnt

  f32x4 acc[2][4];
#pragma unroll
  for (int g = 0; g < 2; ++g)
#pragma unroll
    for (int c = 0; c < 4; ++c) acc[g][c] = (f32x4){0.f, 0.f, 0.f, 0.f};

  for (int k = 0; k < TAPS; ++k) {
    const int cur = k & 1;
    if (k + 1 < TAPS) {
      const unsigned short* g = WP + (k + 1) * 4096;
      __builtin_amdgcn_global_load_lds((GLB const u32*)(g + t * 8),
                                       (LDS u32*)&wbuf[cur ^ 1][t * 8], 16, 0, 0);
      __builtin_amdgcn_global_load_lds((GLB const u32*)(g + (t + 256) * 8),
                                       (LDS u32*)&wbuf[cur ^ 1][(t + 256) * 8], 16, 0, 0);
    }
    const int* np = nbr + (size_t)k * NROW + nb0;
    int i0 = np[0], i1 = np[16];
    if (__ballot(i0 >= 0 || i1 >= 0) != 0ull) {
      const unsigned short* r0 = X + (size_t)(i0 >= 0 ? i0 : NROW) * 64 + lk * 8;
      const unsigned short* r1 = X + (size_t)(i1 >= 0 ? i1 : NROW) * 64 + lk * 8;
      short8 a00 = *(const short8*)r0, a01 = *(const short8*)(r0 + 32);
      short8 a10 = *(const short8*)r1, a11 = *(const short8*)(r1 + 32);
      const unsigned short* wl = &wbuf[cur][lane * 8];
#pragma unroll
      for (int ct = 0; ct < 4; ++ct) {
        short8 b0 = *(const short8*)(wl + ct * 1024);
        short8 b1 = *(const short8*)(wl + ct * 1024 + 512);
        acc[0][ct] = __builtin_amdgcn_mfma_f32_16x16x32_bf16(a00, b0, acc[0][ct], 0, 0, 0);
        acc[0][ct] = __builtin_amdgcn_mfma_f32_16x16x32_bf16(a01, b1, acc[0][ct], 0, 0, 0);
        acc[1][ct] = __builtin_amdgcn_mfma_f32_16x16x32_bf16(a10, b0, acc[1][ct], 0, 0, 0);
        acc[1][ct] = __builtin_amdgcn_mfma_f32_16x16x32_bf16(a11, b1, acc[1][ct], 0, 0, 0);
      }
    }
    __syncthreads();   // staged buffer ready for next tap; wbuf[cur] free for overwrite
  }

  // C/D: col = lane&15 (+ct*16), row = (lane>>4)*4 + reg (+g*16)
#pragma unroll
  for (int g = 0; g < 2; ++g) {
    unsigned short* yp = Y + (size_t)(j0w + g * 16 + lk * 4) * 64 + lrow;
#pragma unroll
    for (int r = 0; r < 4; ++r) {
      yp[r * 64 +  0] = f2bf(acc[g][0][r]);
      yp[r * 64 + 16] = f2bf(acc[g][1][r]);
      yp[r * 64 + 32] = f2bf(acc[g][2][r]);
      yp[r * 64 + 48] = f2bf(acc[g][3][r]);
    }
  }

  // fused IN stats: per-lane sum/sumsq over its 8 rows, batch-split
  float s[4][2], q[4][2];
#pragma unroll
  for (int ct = 0; ct < 4; ++ct) { s[ct][0] = s[ct][1] = q[ct][0] = q[ct][1] = 0.f; }
#pragma unroll
  for (int g = 0; g < 2; ++g) {
    int rowbase = j0w + g * 16 + lk * 4;
#pragma unroll
    for (int r = 0; r < 4; ++r) {
      int bt = (rowbase + r) >= NB;
#pragma unroll
      for (int ct = 0; ct < 4; ++ct) {
        float v = acc[g][ct][r];
        s[ct][bt] += v; q[ct][bt] += v * v;
      }
    }
  }
#pragma unroll
  for (int ct = 0; ct < 4; ++ct)
#pragma unroll
    for (int b = 0; b < 2; ++b) {
      sred[wave][lk][b * 2 + 0][ct * 16 + lrow] = s[ct][b];
      sred[wave][lk][b * 2 + 1][ct * 16 + lrow] = q[ct][b];
    }
  __syncthreads();
  float S = 0.f;
#pragma unroll
  for (int w = 0; w < 4; ++w)
#pragma unroll
    for (int l2 = 0; l2 < 4; ++l2)
      S += sred[w][l2][t >> 6][t & 63];
  atomicAdd(&SM[t], S);
}

// ---- final stage 1: D[k][i] = X[i] . WF[k]  (MFMA GEMM 120064x64 @ 64x27) ----
__global__ __launch_bounds__(256) void k_dfin(const unsigned short* __restrict__ X,
                                              const float* __restrict__ WF,
                                              float* __restrict__ D) {
  const int lane = threadIdx.x & 63, wave = threadIdx.x >> 6;
  const int j0 = blockIdx.x * 64 + wave * 16;
  const int lrow = lane & 15, lk = lane >> 4;
  const unsigned short* rp = X + (size_t)(j0 + lrow) * 64 + lk * 8;
  short8 a0 = *(const short8*)rp;
  short8 a1 = *(const short8*)(rp + 32);
  short8 b[2][2];
#pragma unroll
  for (int ct = 0; ct < 2; ++ct) {
    int col = ct * 16 + lrow;
#pragma unroll
    for (int h = 0; h < 2; ++h) {
#pragma unroll
      for (int e = 0; e < 8; ++e)
        b[ct][h][e] = (col < TAPS) ? (short)f2bf(WF[col * 64 + h * 32 + lk * 8 + e]) : (short)0;
    }
  }
  f32x4 acc0 = {0,0,0,0}, acc1 = {0,0,0,0};
  acc0 = __builtin_amdgcn_mfma_f32_16x16x32_bf16(a0, b[0][0], acc0, 0, 0, 0);
  acc0 = __builtin_amdgcn_mfma_f32_16x16x32_bf16(a1, b[0][1], acc0, 0, 0, 0);
  acc1 = __builtin_amdgcn_mfma_f32_16x16x32_bf16(a0, b[1][0], acc1, 0, 0, 0);
  acc1 = __builtin_amdgcn_mfma_f32_16x16x32_bf16(a1, b[1][1], acc1, 0, 0, 0);
  float* dp0 = D + (size_t)lrow * NROW + j0 + lk * 4;
  float* dp1 = D + (size_t)(16 + lrow) * NROW + j0 + lk * 4;
#pragma unroll
  for (int r = 0; r < 4; ++r) { dp0[r] = acc0[r]; dp1[r] = acc1[r]; }
}

// ---- final stage 2: out[j] = bias + sum_k D[k][nbr[k][j]] ----
__global__ __launch_bounds__(256) void k_gfin(const float* __restrict__ D,
                                              const int* __restrict__ nbr,
                                              const float* __restrict__ BF,
                                              float* __restrict__ out) {
  int j = blockIdx.x * 256 + threadIdx.x;
  if (j >= NPTS) return;
  float acc = BF[0];
#pragma unroll
  for (int k = 0; k < TAPS; ++k) {
    int idx = nbr[(size_t)k * NROW + j];
    if (idx >= 0) acc += D[(size_t)k * NROW + idx];
  }
  out[j] = acc;
}

extern "C" void kernel_launch(void* const* d_in, const int* in_sizes, int n_in,
                              void* d_out, int out_size, void* d_ws, size_t ws_size,
                              hipStream_t stream) {
  (void)in_sizes; (void)n_in; (void)out_size; (void)ws_size;
  const float* feats = (const float*)d_in[0];
  const float* wblk  = (const float*)d_in[1];
  const float* wfin  = (const float*)d_in[2];
  const float* bfin  = (const float*)d_in[3];
  const int* in_idx  = (const int*)d_in[4];
  const int* out_idx = (const int*)d_in[5];

  char* p = (char*)d_ws;
  size_t off = 0;
  auto carve = [&](size_t bytes) {
    void* r = p + off; off += (bytes + 255) & ~(size_t)255; return r;
  };
  int*            nbr = (int*)carve((size_t)TAPS * NROW * 4);                 // 12.97 MB
  unsigned short* Xb  = (unsigned short*)carve((size_t)(NROW + 1) * 64 * 2);  // +1 zero row
  unsigned short* Hb  = (unsigned short*)carve((size_t)(NROW + 1) * 64 * 2);
  unsigned short* H2b = (unsigned short*)carve((size_t)NROW * 64 * 2);
  unsigned short* WP  = (unsigned short*)carve(108u * 4096u * 2);             // 0.88 MB
  float*          D   = (float*)carve((size_t)32 * NROW * 4);                 // 15.4 MB
  float*          SMa = (float*)carve(5 * 256 * 4);                           // SM0..SM4

  float* SM0 = SMa;
  float* SM1 = SMa + 256;
  float* SM2 = SMa + 512;
  float* SM3 = SMa + 768;
  float* SM4 = SMa + 1024;

  hipMemsetAsync(nbr, 0xFF, (size_t)TAPS * NROW * 4, stream);
  hipMemsetAsync(SMa, 0, 5 * 256 * 4, stream);
  hipMemsetAsync(Xb + (size_t)NROW * 64, 0, 128, stream);   // zero row
  hipMemsetAsync(Hb + (size_t)NROW * 64, 0, 128, stream);   // zero row
  k_build_nbr<<<(TAPS * NPTS + 255) / 256, 256, 0, stream>>>(out_idx, in_idx, nbr);
  k_repack<<<1728, 256, 0, stream>>>(wblk, WP);

  // x = relu(IN(feats))
  k_stats1_f32<<<256, 256, 0, stream>>>(feats, SM0);
  k_apply_f2b<<<3750, 256, 0, stream>>>(feats, SM0, Xb);

  // block 0
  k_conv64s<<<NBLK, 256, 0, stream>>>(Xb, WP + 0 * 110592, nbr, Hb, SM1);
  k_apply_bf<<<3750, 256, 0, stream>>>(Hb, SM1, Hb);
  k_conv64s<<<NBLK, 256, 0, stream>>>(Hb, WP + 1 * 110592, nbr, H2b, SM2);
  k_apply_res_bf<<<3750, 256, 0, stream>>>(H2b, SM2, Xb);

  // block 1
  k_conv64s<<<NBLK, 256, 0, stream>>>(Xb, WP + 2 * 110592, nbr, Hb, SM3);
  k_apply_bf<<<3750, 256, 0, stream>>>(Hb, SM3, Hb);
  k_conv64s<<<NBLK, 256, 0, stream>>>(Hb, WP + 3 * 110592, nbr, H2b, SM4);
  k_apply_res_bf<<<3750, 256, 0, stream>>>(H2b, SM4, Xb);

  // final 64->1 conv + bias: D = X.WF^T then gather-sum
  k_dfin<<<NROW / 64, 256, 0, stream>>>(Xb, wfin, D);
  k_gfin<<<NROW / 256, 256, 0, stream>>>(D, nbr, bfin, (float*)d_out);
}